// Round 1
// baseline (272.612 us; speedup 1.0000x reference)
//
#include <hip/hip_runtime.h>

#define PI_F      3.14159265358979323846f
#define TWO_PI_F  6.28318530717958647692f
#define BETA      6.4860766f     // pi*sqrt((3/2)^2*(1.5)^2 - 0.8)
#define NM        204800
#define TSTRIDE   642

__device__ __forceinline__ float2 cmulf(float2 a, float2 b){
    return make_float2(a.x*b.x - a.y*b.y, a.x*b.y + a.y*b.x);
}

__device__ __forceinline__ float i0_dev(float x){
    if (x < 3.75f){
        float t = x * (1.0f/3.75f); t *= t;
        return 1.0f + t*(3.5156229f + t*(3.0899424f + t*(1.2067492f +
                     t*(0.2659732f + t*(0.0360768f + t*0.0045813f)))));
    } else {
        float u = 3.75f / x;
        float p = 0.39894228f + u*(0.01328592f + u*(0.00225319f + u*(-0.00157565f +
                  u*(0.00916281f + u*(-0.02057706f + u*(0.02635537f +
                  u*(-0.01647633f + u*0.00392377f)))))));
        return p * expf(x) * rsqrtf(x);
    }
}

__device__ __forceinline__ float kbw(float d){
    float dd = d * (2.0f/3.0f);
    float t = 1.0f - dd*dd;
    if (t <= 0.0f) return 0.0f;
    return i0_dev(BETA * sqrtf(t)) * (1.0f/3.0f);
}

// K0: 1D deapodization profile a1[320]
__global__ void k_deapod(float* __restrict__ a1){
    int i = threadIdx.x;
    if (i >= 320) return;
    float u = (i - 160.0f) * (1.0f/640.0f);
    float v = 3.0f * PI_F * u;
    float q = v*v - BETA*BETA;
    float a;
    if (q >= 0.0f){
        float z = sqrtf(q);
        a = (z > 1e-20f) ? (sinf(z)/z) : 1.0f;
    } else {
        float s = sqrtf(-q);
        a = (expf(s) - expf(-s)) / (2.0f*s);
    }
    a1[i] = a;
}

// K1: coil images, deapodize, fold (-1)^(y+x) input modulation and 1/G
// bufA layout: [16][320][320] complex
__global__ __launch_bounds__(256) void k_prep(const float2* __restrict__ xin,
                                              const float2* __restrict__ csm,
                                              const float* __restrict__ a1,
                                              float2* __restrict__ bufA){
    int idx = blockIdx.x*256 + threadIdx.x;       // exactly 16*320*320 threads
    int c  = idx / 102400;
    int rr = idx - c*102400;
    int yi = rr / 320;
    int xi = rr - yi*320;
    float2 xv = xin[rr];
    float2 cv = csm[idx];
    float sg = ((yi + xi) & 1) ? -1.0f : 1.0f;
    float scale = sg / (a1[yi] * a1[xi] * 640.0f);
    float2 o;
    o.x = (cv.x*xv.x - cv.y*xv.y) * scale;
    o.y = (cv.x*xv.y + cv.y*xv.x) * scale;
    bufA[idx] = o;
}

// 8 parallel 640-pt FFTs over tile rows. Entry: tile[f][n] = x[n].
// Exit: tile[f][k] = X[k] * (-1)^k. Requires blockDim.x == 1024.
__device__ __forceinline__ void fft640_block(float2 (*tile)[TSTRIDE]){
    int tid = threadIdx.x;
    int f = tid >> 7;
    int t = tid & 127;
    float2 xr[5], r[5];
    #pragma unroll
    for (int n1=0;n1<5;n1++) xr[n1] = tile[f][t + 128*n1];
    const float c5r[5] = {1.0f, 0.30901699f, -0.80901699f, -0.80901699f, 0.30901699f};
    const float c5i[5] = {0.0f, -0.95105652f, -0.58778525f, 0.58778525f, 0.95105652f};
    #pragma unroll
    for (int k1=0;k1<5;k1++){
        float sx = xr[0].x, sy = xr[0].y;
        #pragma unroll
        for (int n1=1;n1<5;n1++){
            const int j = (n1*k1) % 5;
            sx += xr[n1].x*c5r[j] - xr[n1].y*c5i[j];
            sy += xr[n1].x*c5i[j] + xr[n1].y*c5r[j];
        }
        r[k1] = make_float2(sx, sy);
    }
    #pragma unroll
    for (int k1=1;k1<5;k1++){
        float ang = -TWO_PI_F * (float)(t*k1) * (1.0f/640.0f);
        float sn, cs; sincosf(ang, &sn, &cs);
        r[k1] = cmulf(r[k1], make_float2(cs, sn));
    }
    // own-slot writes only (same index set as own reads) -> no barrier needed before
    #pragma unroll
    for (int k1=0;k1<5;k1++) tile[f][k1*128 + t] = r[k1];
    __syncthreads();
    for (int h=64; h>=1; h>>=1){
        float2 p[5];
        #pragma unroll
        for (int k1=0;k1<5;k1++) p[k1] = tile[f][k1*128 + (t^h)];
        bool up = (t & h) != 0;
        float2 w = make_float2(1.0f, 0.0f);
        if (up){
            float ang = -PI_F * (float)(t & (h-1)) / (float)h;
            float sn, cs; sincosf(ang, &sn, &cs);
            w = make_float2(cs, sn);
        }
        #pragma unroll
        for (int k1=0;k1<5;k1++){
            if (!up){
                r[k1] = make_float2(r[k1].x + p[k1].x, r[k1].y + p[k1].y);
            } else {
                float2 d = make_float2(p[k1].x - r[k1].x, p[k1].y - r[k1].y);
                r[k1] = cmulf(d, w);
            }
        }
        __syncthreads();
        if (h > 1){
            #pragma unroll
            for (int k1=0;k1<5;k1++) tile[f][k1*128 + t] = r[k1];
            __syncthreads();
        }
    }
    int br = __brev((unsigned)t) >> 25;   // bit-reverse 7 bits
    #pragma unroll
    for (int k1=0;k1<5;k1++){
        int g = k1 + 5*br;
        float sg = (g & 1) ? -1.0f : 1.0f;
        tile[f][g] = make_float2(r[k1].x*sg, r[k1].y*sg);
    }
    __syncthreads();
}

// K2: FFT along x for each (c, y) row; write transposed bufB[c][kx][y]
// bufA: [16][320][320] (x index 160..479 of full grid), bufB: [16][640][320]
__global__ __launch_bounds__(1024) void k_fft1(const float2* __restrict__ bufA,
                                               float2* __restrict__ bufB){
    __shared__ float2 tile[8][TSTRIDE];
    int b  = blockIdx.x;            // 16 coils * 40 row-octets
    int c  = b / 40;
    int y0 = (b - c*40) * 8;
    int tid = threadIdx.x;
    for (int idx = tid; idx < 8*640; idx += 1024){
        int f = idx / 640;
        int n = idx - f*640;
        float2 v = make_float2(0.0f, 0.0f);
        if (n >= 160 && n < 480)
            v = bufA[(c*320 + y0 + f)*320 + (n - 160)];
        tile[f][n] = v;
    }
    __syncthreads();
    fft640_block(tile);
    for (int idx = tid; idx < 640*8; idx += 1024){
        int kx = idx >> 3;
        int f  = idx & 7;
        bufB[(c*640 + kx)*320 + (y0 + f)] = tile[f][kx];
    }
}

// K3: FFT along y for each (c, kx); write coil-interleaved kspI[ky][kx][c]
// block handles 8 coils (one half) of one kx row
__global__ __launch_bounds__(1024) void k_fft2(const float2* __restrict__ bufB,
                                               float2* __restrict__ kspI){
    __shared__ float2 tile[8][TSTRIDE];
    int b  = blockIdx.x;            // 640 kx * 2 coil-halves
    int kx = b >> 1;
    int c0 = (b & 1) * 8;
    int tid = threadIdx.x;
    for (int idx = tid; idx < 8*640; idx += 1024){
        int f = idx / 640;
        int n = idx - f*640;
        float2 v = make_float2(0.0f, 0.0f);
        if (n >= 160 && n < 480)
            v = bufB[((c0 + f)*640 + kx)*320 + (n - 160)];
        tile[f][n] = v;
    }
    __syncthreads();
    fft640_block(tile);
    for (int idx = tid; idx < 640*8; idx += 1024){
        int ky = idx >> 3;
        int f  = idx & 7;
        kspI[(ky*640 + kx)*16 + c0 + f] = tile[f][ky];
    }
}

// K5: KB degridding + sqrt(dcf); out[c][m][2]
__global__ __launch_bounds__(256) void k_interp(const float* __restrict__ traj,
                                                const float* __restrict__ dcf,
                                                const float2* __restrict__ kspI,
                                                float2* __restrict__ out){
    int m = blockIdx.x*256 + threadIdx.x;     // exactly NM threads
    float py = traj[m]      * 640.0f + 320.0f;
    float px = traj[NM + m] * 640.0f + 320.0f;
    float cy = rintf(py), cx = rintf(px);
    float wy[3], wx[3];
    int iy[3], ix[3];
    #pragma unroll
    for (int j=0;j<3;j++){
        float o = (float)(j-1);
        wy[j] = kbw(cy + o - py);
        wx[j] = kbw(cx + o - px);
        int yy = (int)cy + (j-1); yy %= 640; if (yy < 0) yy += 640; iy[j] = yy;
        int xx = (int)cx + (j-1); xx %= 640; if (xx < 0) xx += 640; ix[j] = xx;
    }
    float2 acc[16];
    #pragma unroll
    for (int c=0;c<16;c++) acc[c] = make_float2(0.0f, 0.0f);
    #pragma unroll
    for (int jy=0;jy<3;jy++){
        #pragma unroll
        for (int jx=0;jx<3;jx++){
            float w = wy[jy]*wx[jx];
            const float4* p4 = (const float4*)(kspI + (iy[jy]*640 + ix[jx])*16);
            #pragma unroll
            for (int q=0;q<8;q++){
                float4 v = p4[q];
                acc[2*q].x   = fmaf(w, v.x, acc[2*q].x);
                acc[2*q].y   = fmaf(w, v.y, acc[2*q].y);
                acc[2*q+1].x = fmaf(w, v.z, acc[2*q+1].x);
                acc[2*q+1].y = fmaf(w, v.w, acc[2*q+1].y);
            }
        }
    }
    float s = sqrtf(dcf[m]);
    #pragma unroll
    for (int c=0;c<16;c++)
        out[c*NM + m] = make_float2(acc[c].x*s, acc[c].y*s);
}

extern "C" void kernel_launch(void* const* d_in, const int* in_sizes, int n_in,
                              void* d_out, int out_size, void* d_ws, size_t ws_size,
                              hipStream_t stream) {
    (void)in_sizes; (void)n_in; (void)out_size; (void)ws_size;
    const float* x    = (const float*)d_in[0];   // [320,320,2]
    const float* csm  = (const float*)d_in[1];   // [16,320,320,2]
    const float* traj = (const float*)d_in[2];   // [2,204800]
    const float* dcf  = (const float*)d_in[3];   // [204800]
    float* out = (float*)d_out;                  // [16,204800,2]

    char* ws = (char*)d_ws;
    float*  a1   = (float*)ws;                               // 320 floats
    float2* bufA = (float2*)(ws + 2048);                     // 13.1 MB  [16][320][320]
    float2* kspI = (float2*)(ws + 2048);                     // 52.4 MB  [640][640][16] (overlaps dead bufA)
    float2* bufB = (float2*)(ws + 2048 + 52428800ull);       // 26.2 MB  [16][640][320]

    k_deapod<<<1, 320, 0, stream>>>(a1);
    k_prep  <<<6400, 256, 0, stream>>>((const float2*)x, (const float2*)csm, a1, bufA);
    k_fft1  <<<640, 1024, 0, stream>>>(bufA, bufB);
    k_fft2  <<<1280, 1024, 0, stream>>>(bufB, kspI);
    k_interp<<<800, 256, 0, stream>>>(traj, dcf, kspI, (float2*)out);
}

// Round 2
// 208.733 us; speedup vs baseline: 1.3060x; 1.3060x over previous
//
#include <hip/hip_runtime.h>

#define PI_F      3.14159265358979323846f
#define TWO_PI_F  6.28318530717958647692f
#define BETA      6.4860766f     // pi*sqrt((3/2)^2*(1.5)^2 - 0.8)
#define NM        204800
#define TSTRIDE   642
#define NBIN      1600           // 40x40 bins of 16x16 k-space tiles

__device__ __forceinline__ float2 cmulf(float2 a, float2 b){
    return make_float2(a.x*b.x - a.y*b.y, a.x*b.y + a.y*b.x);
}

__device__ __forceinline__ float i0_dev(float x){
    if (x < 3.75f){
        float t = x * (1.0f/3.75f); t *= t;
        return 1.0f + t*(3.5156229f + t*(3.0899424f + t*(1.2067492f +
                     t*(0.2659732f + t*(0.0360768f + t*0.0045813f)))));
    } else {
        float u = 3.75f / x;
        float p = 0.39894228f + u*(0.01328592f + u*(0.00225319f + u*(-0.00157565f +
                  u*(0.00916281f + u*(-0.02057706f + u*(0.02635537f +
                  u*(-0.01647633f + u*0.00392377f)))))));
        return p * expf(x) * rsqrtf(x);
    }
}

__device__ __forceinline__ float kbw(float d){
    float dd = d * (2.0f/3.0f);
    float t = 1.0f - dd*dd;
    if (t <= 0.0f) return 0.0f;
    return i0_dev(BETA * sqrtf(t)) * (1.0f/3.0f);
}

// K0: 1D deapodization profile a1[320]
__global__ void k_deapod(float* __restrict__ a1){
    int i = threadIdx.x;
    if (i >= 320) return;
    float u = (i - 160.0f) * (1.0f/640.0f);
    float v = 3.0f * PI_F * u;
    float q = v*v - BETA*BETA;
    float a;
    if (q >= 0.0f){
        float z = sqrtf(q);
        a = (z > 1e-20f) ? (sinf(z)/z) : 1.0f;
    } else {
        float s = sqrtf(-q);
        a = (expf(s) - expf(-s)) / (2.0f*s);
    }
    a1[i] = a;
}

// K1: coil images, deapodize, fold (-1)^(y+x) input modulation and 1/G
__global__ __launch_bounds__(256) void k_prep(const float2* __restrict__ xin,
                                              const float2* __restrict__ csm,
                                              const float* __restrict__ a1,
                                              float2* __restrict__ bufA){
    int idx = blockIdx.x*256 + threadIdx.x;       // exactly 16*320*320 threads
    int c  = idx / 102400;
    int rr = idx - c*102400;
    int yi = rr / 320;
    int xi = rr - yi*320;
    float2 xv = xin[rr];
    float2 cv = csm[idx];
    float sg = ((yi + xi) & 1) ? -1.0f : 1.0f;
    float scale = sg / (a1[yi] * a1[xi] * 640.0f);
    float2 o;
    o.x = (cv.x*xv.x - cv.y*xv.y) * scale;
    o.y = (cv.x*xv.y + cv.y*xv.x) * scale;
    bufA[idx] = o;
}

// 8 parallel 640-pt FFTs over tile rows. Entry: tile[f][n] = x[n].
// Exit: tile[f][k] = X[k] * (-1)^k. Requires blockDim.x == 1024.
__device__ __forceinline__ void fft640_block(float2 (*tile)[TSTRIDE]){
    int tid = threadIdx.x;
    int f = tid >> 7;
    int t = tid & 127;
    float2 xr[5], r[5];
    #pragma unroll
    for (int n1=0;n1<5;n1++) xr[n1] = tile[f][t + 128*n1];
    const float c5r[5] = {1.0f, 0.30901699f, -0.80901699f, -0.80901699f, 0.30901699f};
    const float c5i[5] = {0.0f, -0.95105652f, -0.58778525f, 0.58778525f, 0.95105652f};
    #pragma unroll
    for (int k1=0;k1<5;k1++){
        float sx = xr[0].x, sy = xr[0].y;
        #pragma unroll
        for (int n1=1;n1<5;n1++){
            const int j = (n1*k1) % 5;
            sx += xr[n1].x*c5r[j] - xr[n1].y*c5i[j];
            sy += xr[n1].x*c5i[j] + xr[n1].y*c5r[j];
        }
        r[k1] = make_float2(sx, sy);
    }
    #pragma unroll
    for (int k1=1;k1<5;k1++){
        float ang = -TWO_PI_F * (float)(t*k1) * (1.0f/640.0f);
        float sn, cs; sincosf(ang, &sn, &cs);
        r[k1] = cmulf(r[k1], make_float2(cs, sn));
    }
    #pragma unroll
    for (int k1=0;k1<5;k1++) tile[f][k1*128 + t] = r[k1];
    __syncthreads();
    for (int h=64; h>=1; h>>=1){
        float2 p[5];
        #pragma unroll
        for (int k1=0;k1<5;k1++) p[k1] = tile[f][k1*128 + (t^h)];
        bool up = (t & h) != 0;
        float2 w = make_float2(1.0f, 0.0f);
        if (up){
            float ang = -PI_F * (float)(t & (h-1)) / (float)h;
            float sn, cs; sincosf(ang, &sn, &cs);
            w = make_float2(cs, sn);
        }
        #pragma unroll
        for (int k1=0;k1<5;k1++){
            if (!up){
                r[k1] = make_float2(r[k1].x + p[k1].x, r[k1].y + p[k1].y);
            } else {
                float2 d = make_float2(p[k1].x - r[k1].x, p[k1].y - r[k1].y);
                r[k1] = cmulf(d, w);
            }
        }
        __syncthreads();
        if (h > 1){
            #pragma unroll
            for (int k1=0;k1<5;k1++) tile[f][k1*128 + t] = r[k1];
            __syncthreads();
        }
    }
    int br = __brev((unsigned)t) >> 25;   // bit-reverse 7 bits
    #pragma unroll
    for (int k1=0;k1<5;k1++){
        int g = k1 + 5*br;
        float sg = (g & 1) ? -1.0f : 1.0f;
        tile[f][g] = make_float2(r[k1].x*sg, r[k1].y*sg);
    }
    __syncthreads();
}

// K2: FFT along x for each (c, y) row; write transposed bufB[c][kx][y]
__global__ __launch_bounds__(1024) void k_fft1(const float2* __restrict__ bufA,
                                               float2* __restrict__ bufB){
    __shared__ float2 tile[8][TSTRIDE];
    int b  = blockIdx.x;            // 16 coils * 40 row-octets
    int c  = b / 40;
    int y0 = (b - c*40) * 8;
    int tid = threadIdx.x;
    for (int idx = tid; idx < 8*640; idx += 1024){
        int f = idx / 640;
        int n = idx - f*640;
        float2 v = make_float2(0.0f, 0.0f);
        if (n >= 160 && n < 480)
            v = bufA[(c*320 + y0 + f)*320 + (n - 160)];
        tile[f][n] = v;
    }
    __syncthreads();
    fft640_block(tile);
    for (int idx = tid; idx < 640*8; idx += 1024){
        int kx = idx >> 3;
        int f  = idx & 7;
        bufB[(c*640 + kx)*320 + (y0 + f)] = tile[f][kx];
    }
}

// K3: FFT along y for each (c, kx); write coil-interleaved kspI[ky][kx][c]
__global__ __launch_bounds__(1024) void k_fft2(const float2* __restrict__ bufB,
                                               float2* __restrict__ kspI){
    __shared__ float2 tile[8][TSTRIDE];
    int b  = blockIdx.x;            // 640 kx * 2 coil-halves
    int kx = b >> 1;
    int c0 = (b & 1) * 8;
    int tid = threadIdx.x;
    for (int idx = tid; idx < 8*640; idx += 1024){
        int f = idx / 640;
        int n = idx - f*640;
        float2 v = make_float2(0.0f, 0.0f);
        if (n >= 160 && n < 480)
            v = bufB[((c0 + f)*640 + kx)*320 + (n - 160)];
        tile[f][n] = v;
    }
    __syncthreads();
    fft640_block(tile);
    for (int idx = tid; idx < 640*8; idx += 1024){
        int ky = idx >> 3;
        int f  = idx & 7;
        kspI[(ky*640 + kx)*16 + c0 + f] = tile[f][ky];
    }
}

// ---- binning pipeline ----

__device__ __forceinline__ int bin_of(float py, float px){
    int yy = (int)rintf(py); yy %= 640; if (yy < 0) yy += 640;
    int xx = (int)rintf(px); xx %= 640; if (xx < 0) xx += 640;
    return (yy >> 4) * 40 + (xx >> 4);
}

__global__ __launch_bounds__(256) void k_zero(int* __restrict__ counts){
    int i = blockIdx.x*256 + threadIdx.x;
    if (i < NBIN) counts[i] = 0;
}

__global__ __launch_bounds__(256) void k_hist(const float* __restrict__ traj,
                                              int* __restrict__ counts){
    int m = blockIdx.x*256 + threadIdx.x;     // exactly NM threads
    float py = traj[m]      * 640.0f + 320.0f;
    float px = traj[NM + m] * 640.0f + 320.0f;
    atomicAdd(&counts[bin_of(py, px)], 1);
}

// single block, 1024 threads: exclusive scan of counts[1600] -> offsets[1600]
__global__ __launch_bounds__(1024) void k_scan(const int* __restrict__ counts,
                                               int* __restrict__ offsets){
    __shared__ int s[1024];
    int tid = threadIdx.x;
    int c0 = (2*tid   < NBIN) ? counts[2*tid]   : 0;
    int c1 = (2*tid+1 < NBIN) ? counts[2*tid+1] : 0;
    int sum = c0 + c1;
    s[tid] = sum;
    __syncthreads();
    for (int off = 1; off < 1024; off <<= 1){
        int t = 0;
        if (tid >= off) t = s[tid - off];
        __syncthreads();
        if (tid >= off) s[tid] += t;
        __syncthreads();
    }
    int excl = s[tid] - sum;
    if (2*tid   < NBIN) offsets[2*tid]   = excl;
    if (2*tid+1 < NBIN) offsets[2*tid+1] = excl + c0;
}

// scatter: sorted traj records + inverse permutation (destroys offsets)
__global__ __launch_bounds__(256) void k_scatter(const float* __restrict__ traj,
                                                 const float* __restrict__ dcf,
                                                 int* __restrict__ offsets,
                                                 float4* __restrict__ st,
                                                 int* __restrict__ inv){
    int m = blockIdx.x*256 + threadIdx.x;     // exactly NM threads
    float py = traj[m]      * 640.0f + 320.0f;
    float px = traj[NM + m] * 640.0f + 320.0f;
    int pos = atomicAdd(&offsets[bin_of(py, px)], 1);
    st[pos] = make_float4(py, px, sqrtf(dcf[m]), 0.0f);
    inv[m] = pos;
}

// binned KB degridding: 2 threads per sorted sample (8 coils each),
// results staged coil-contiguous: staged[i][16] (one 128B line per sample)
__global__ __launch_bounds__(256) void k_interp2(const float4* __restrict__ st,
                                                 const float2* __restrict__ kspI,
                                                 float2* __restrict__ staged){
    int g = blockIdx.x*256 + threadIdx.x;     // 2*NM threads
    int i = g >> 1;
    int h = g & 1;
    float4 s4 = st[i];
    float py = s4.x, px = s4.y, sc = s4.z;
    float cy = rintf(py), cx = rintf(px);
    float wy[3], wx[3];
    int iy[3], ix[3];
    #pragma unroll
    for (int j=0;j<3;j++){
        float o = (float)(j-1);
        wy[j] = kbw(cy + o - py);
        wx[j] = kbw(cx + o - px);
        int yy = (int)cy + (j-1); yy %= 640; if (yy < 0) yy += 640; iy[j] = yy;
        int xx = (int)cx + (j-1); xx %= 640; if (xx < 0) xx += 640; ix[j] = xx;
    }
    float2 acc[8];
    #pragma unroll
    for (int c=0;c<8;c++) acc[c] = make_float2(0.0f, 0.0f);
    #pragma unroll
    for (int jy=0;jy<3;jy++){
        #pragma unroll
        for (int jx=0;jx<3;jx++){
            float w = wy[jy]*wx[jx];
            const float4* p4 = (const float4*)(kspI + (iy[jy]*640 + ix[jx])*16 + h*8);
            #pragma unroll
            for (int q=0;q<4;q++){
                float4 v = p4[q];
                acc[2*q].x   = fmaf(w, v.x, acc[2*q].x);
                acc[2*q].y   = fmaf(w, v.y, acc[2*q].y);
                acc[2*q+1].x = fmaf(w, v.z, acc[2*q+1].x);
                acc[2*q+1].y = fmaf(w, v.w, acc[2*q+1].y);
            }
        }
    }
    float2* o = staged + i*16 + h*8;
    #pragma unroll
    for (int c=0;c<8;c++)
        o[c] = make_float2(acc[c].x*sc, acc[c].y*sc);
}

// un-permute: thread per m reads its full 128B staged line (single touch),
// writes out[c][m] coalesced per coil
__global__ __launch_bounds__(256) void k_unperm(const int* __restrict__ inv,
                                                const float2* __restrict__ staged,
                                                float2* __restrict__ out){
    int m = blockIdx.x*256 + threadIdx.x;     // exactly NM threads
    int j = inv[m];
    const float4* p4 = (const float4*)(staged + j*16);
    #pragma unroll
    for (int q=0;q<8;q++){
        float4 v = p4[q];
        out[(2*q)*NM + m]   = make_float2(v.x, v.y);
        out[(2*q+1)*NM + m] = make_float2(v.z, v.w);
    }
}

extern "C" void kernel_launch(void* const* d_in, const int* in_sizes, int n_in,
                              void* d_out, int out_size, void* d_ws, size_t ws_size,
                              hipStream_t stream) {
    (void)in_sizes; (void)n_in; (void)out_size; (void)ws_size;
    const float* x    = (const float*)d_in[0];   // [320,320,2]
    const float* csm  = (const float*)d_in[1];   // [16,320,320,2]
    const float* traj = (const float*)d_in[2];   // [2,204800]
    const float* dcf  = (const float*)d_in[3];   // [204800]
    float* out = (float*)d_out;                  // [16,204800,2]

    char* ws = (char*)d_ws;
    float*  a1   = (float*)ws;                               // 320 floats
    float2* bufA = (float2*)(ws + 2048);                     // 13.1 MB [16][320][320]
    float2* kspI = (float2*)(ws + 2048);                     // 52.4 MB [640][640][16] (overlaps dead bufA)
    float2* bufB = (float2*)(ws + 2048 + 52428800ull);       // 26.2 MB [16][640][320]
    float2* staged = bufB;                                   // 26.2 MB (bufB dead after fft2)
    char* bb = ws + 2048 + 52428800ull + 26214400ull;
    int*    counts  = (int*)bb;                              // 6.4 KB
    int*    offsets = (int*)(bb + 8192);                     // 6.4 KB
    int*    inv     = (int*)(bb + 16384);                    // 0.8 MB
    float4* st      = (float4*)(bb + 16384 + 819200);        // 3.3 MB

    // binning (independent of FFT chain)
    k_zero   <<<7, 256, 0, stream>>>(counts);
    k_hist   <<<800, 256, 0, stream>>>(traj, counts);
    k_scan   <<<1, 1024, 0, stream>>>(counts, offsets);
    k_scatter<<<800, 256, 0, stream>>>(traj, dcf, offsets, st, inv);

    // image -> oversampled k-space
    k_deapod<<<1, 320, 0, stream>>>(a1);
    k_prep  <<<6400, 256, 0, stream>>>((const float2*)x, (const float2*)csm, a1, bufA);
    k_fft1  <<<640, 1024, 0, stream>>>(bufA, bufB);
    k_fft2  <<<1280, 1024, 0, stream>>>(bufB, kspI);

    // binned degridding + un-permute
    k_interp2<<<1600, 256, 0, stream>>>(st, kspI, staged);
    k_unperm <<<800, 256, 0, stream>>>(inv, staged, (float2*)out);
}

// Round 3
// 175.098 us; speedup vs baseline: 1.5569x; 1.1921x over previous
//
#include <hip/hip_runtime.h>

#define PI_F      3.14159265358979323846f
#define TWO_PI_F  6.28318530717958647692f
#define BETA      6.4860766f     // pi*sqrt((3/2)^2*(1.5)^2 - 0.8)
#define NM        204800
#define TSTRIDE   642
#define NBIN      1600           // 40x40 bins of 16x16 k-space tiles
#define HALO      18

__device__ __forceinline__ float2 cmulf(float2 a, float2 b){
    return make_float2(a.x*b.x - a.y*b.y, a.x*b.y + a.y*b.x);
}

__device__ __forceinline__ float i0_dev(float x){
    if (x < 3.75f){
        float t = x * (1.0f/3.75f); t *= t;
        return 1.0f + t*(3.5156229f + t*(3.0899424f + t*(1.2067492f +
                     t*(0.2659732f + t*(0.0360768f + t*0.0045813f)))));
    } else {
        float u = 3.75f / x;
        float p = 0.39894228f + u*(0.01328592f + u*(0.00225319f + u*(-0.00157565f +
                  u*(0.00916281f + u*(-0.02057706f + u*(0.02635537f +
                  u*(-0.01647633f + u*0.00392377f)))))));
        return p * expf(x) * rsqrtf(x);
    }
}

__device__ __forceinline__ float kbw(float d){
    float dd = d * (2.0f/3.0f);
    float t = 1.0f - dd*dd;
    if (t <= 0.0f) return 0.0f;
    return i0_dev(BETA * sqrtf(t)) * (1.0f/3.0f);
}

// K0: deapod reciprocal profile ia1[320] (= 1/(a1*sqrt(640))) + zero bin counts
__global__ __launch_bounds__(1024) void k_init(float* __restrict__ ia1,
                                               int* __restrict__ counts){
    int i = threadIdx.x;
    if (i < 320){
        float u = (i - 160.0f) * (1.0f/640.0f);
        float v = 3.0f * PI_F * u;
        float q = v*v - BETA*BETA;
        float a;
        if (q >= 0.0f){
            float z = sqrtf(q);
            a = (z > 1e-20f) ? (sinf(z)/z) : 1.0f;
        } else {
            float s = sqrtf(-q);
            a = (expf(s) - expf(-s)) / (2.0f*s);
        }
        ia1[i] = 1.0f / (a * 25.298221281347036f);   // sqrt(640)
    }
    for (int j = i; j < NBIN; j += 1024) counts[j] = 0;
}

// ---- FFT: 8 parallel 640-pt FFTs per 1024-thread block ----
// Entry: tile[f][n] = x[n]. Exit: tile[f][k] = X[k] * (-1)^k.
// tw[j] = exp(-2*pi*i*j/640) built per block before the caller's barrier.
__device__ __forceinline__ void fft640_core(float2 (*tile)[TSTRIDE],
                                            const float2* __restrict__ tw){
    const int tid = threadIdx.x;
    const int f = tid >> 7;
    const int t = tid & 127;
    float2 r[5];
    {
        float2 xr[5];
        #pragma unroll
        for (int n1=0;n1<5;n1++) xr[n1] = tile[f][t + 128*n1];
        const float c5r[5] = {1.0f, 0.30901699f, -0.80901699f, -0.80901699f, 0.30901699f};
        const float c5i[5] = {0.0f, -0.95105652f, -0.58778525f, 0.58778525f, 0.95105652f};
        #pragma unroll
        for (int k1=0;k1<5;k1++){
            float sx = xr[0].x, sy = xr[0].y;
            #pragma unroll
            for (int n1=1;n1<5;n1++){
                const int j = (n1*k1) % 5;
                sx += xr[n1].x*c5r[j] - xr[n1].y*c5i[j];
                sy += xr[n1].x*c5i[j] + xr[n1].y*c5r[j];
            }
            r[k1] = make_float2(sx, sy);
        }
    }
    // main twiddle e^{-2pi i t k1/640} from table (t*k1 <= 508 < 640)
    #pragma unroll
    for (int k1=1;k1<5;k1++) r[k1] = cmulf(r[k1], tw[t*k1]);

    // stage h=64 (cross-wave) via LDS; w64 = exp(-i*pi*(t&63)/64) = tw[5*(t&63)]
    #pragma unroll
    for (int k1=0;k1<5;k1++) tile[f][k1*128 + t] = r[k1];
    float2 w = tw[(t & 63)*5];
    __syncthreads();
    {
        bool up = (t & 64) != 0;
        #pragma unroll
        for (int k1=0;k1<5;k1++){
            float2 p = tile[f][k1*128 + (t^64)];
            if (!up) r[k1] = make_float2(r[k1].x + p.x, r[k1].y + p.y);
            else     r[k1] = cmulf(make_float2(p.x - r[k1].x, p.y - r[k1].y), w);
        }
    }
    // stages h=32..1 within-wave via shfl_xor; w_h = w_{2h}^2 * (-1)^{(t&h)!=0}
    #pragma unroll
    for (int h=32; h>=1; h >>= 1){
        w = cmulf(w, w);
        bool up = (t & h) != 0;
        if (up){ w.x = -w.x; w.y = -w.y; }
        #pragma unroll
        for (int k1=0;k1<5;k1++){
            float px = __shfl_xor(r[k1].x, h);
            float py = __shfl_xor(r[k1].y, h);
            if (!up) r[k1] = make_float2(r[k1].x + px, r[k1].y + py);
            else     r[k1] = cmulf(make_float2(px - r[k1].x, py - r[k1].y), w);
        }
    }
    __syncthreads();   // ensure all h=64 reads done before overwrite
    int br = __brev((unsigned)t) >> 25;   // bit-reverse 7 bits
    #pragma unroll
    for (int k1=0;k1<5;k1++){
        int g = k1 + 5*br;
        float sg = (g & 1) ? -1.0f : 1.0f;
        tile[f][g] = make_float2(r[k1].x*sg, r[k1].y*sg);
    }
    __syncthreads();
}

// K1: fused prep + FFT along x for image rows; write transposed bufB[c][kx][y]
__global__ __launch_bounds__(1024) void k_fft1(const float2* __restrict__ x,
                                               const float2* __restrict__ csm,
                                               const float* __restrict__ ia1,
                                               float2* __restrict__ bufB){
    __shared__ float2 tile[8][TSTRIDE];
    __shared__ float2 tw[640];
    int b  = blockIdx.x;            // 16 coils * 40 row-octets
    int c  = b / 40;
    int y0 = (b - c*40) * 8;
    int tid = threadIdx.x;
    for (int j = tid; j < 640; j += 1024){
        float sn, cs; sincosf((float)j * (-TWO_PI_F/640.0f), &sn, &cs);
        tw[j] = make_float2(cs, sn);
    }
    for (int idx = tid; idx < 8*640; idx += 1024){
        int f = idx / 640;
        int n = idx - f*640;
        float2 v = make_float2(0.0f, 0.0f);
        if (n >= 160 && n < 480){
            int y  = y0 + f;
            int xi = n - 160;
            int rr = y*320 + xi;
            float2 xv = x[rr];
            float2 cv = csm[c*102400 + rr];
            float scl = ia1[y] * ia1[xi];
            if ((y + xi) & 1) scl = -scl;
            v.x = (cv.x*xv.x - cv.y*xv.y) * scl;
            v.y = (cv.x*xv.y + cv.y*xv.x) * scl;
        }
        tile[f][n] = v;
    }
    __syncthreads();
    fft640_core(tile, tw);
    for (int idx = tid; idx < 640*8; idx += 1024){
        int kx = idx >> 3;
        int f  = idx & 7;
        bufB[(c*640 + kx)*320 + (y0 + f)] = tile[f][kx];
    }
}

// K2: FFT along y; write coil-interleaved kspI[ky][kx][c]
__global__ __launch_bounds__(1024) void k_fft2(const float2* __restrict__ bufB,
                                               float2* __restrict__ kspI){
    __shared__ float2 tile[8][TSTRIDE];
    __shared__ float2 tw[640];
    int b  = blockIdx.x;            // 640 kx * 2 coil-halves
    int kx = b >> 1;
    int c0 = (b & 1) * 8;
    int tid = threadIdx.x;
    for (int j = tid; j < 640; j += 1024){
        float sn, cs; sincosf((float)j * (-TWO_PI_F/640.0f), &sn, &cs);
        tw[j] = make_float2(cs, sn);
    }
    for (int idx = tid; idx < 8*640; idx += 1024){
        int f = idx / 640;
        int n = idx - f*640;
        float2 v = make_float2(0.0f, 0.0f);
        if (n >= 160 && n < 480)
            v = bufB[((c0 + f)*640 + kx)*320 + (n - 160)];
        tile[f][n] = v;
    }
    __syncthreads();
    fft640_core(tile, tw);
    for (int idx = tid; idx < 640*8; idx += 1024){
        int ky = idx >> 3;
        int f  = idx & 7;
        kspI[(ky*640 + kx)*16 + c0 + f] = tile[f][ky];
    }
}

// ---- binning pipeline ----

__device__ __forceinline__ int bin_of(float py, float px){
    int yy = (int)rintf(py); yy %= 640; if (yy < 0) yy += 640;
    int xx = (int)rintf(px); xx %= 640; if (xx < 0) xx += 640;
    return (yy >> 4) * 40 + (xx >> 4);
}

__global__ __launch_bounds__(256) void k_hist(const float* __restrict__ traj,
                                              int* __restrict__ counts){
    int m = blockIdx.x*256 + threadIdx.x;     // exactly NM threads
    float py = traj[m]      * 640.0f + 320.0f;
    float px = traj[NM + m] * 640.0f + 320.0f;
    atomicAdd(&counts[bin_of(py, px)], 1);
}

// single block: exclusive scan of counts[1600] -> offsets (scratch) + off0 (kept)
__global__ __launch_bounds__(1024) void k_scan(const int* __restrict__ counts,
                                               int* __restrict__ offsets,
                                               int* __restrict__ off0){
    __shared__ int s[1024];
    int tid = threadIdx.x;
    int c0 = (2*tid   < NBIN) ? counts[2*tid]   : 0;
    int c1 = (2*tid+1 < NBIN) ? counts[2*tid+1] : 0;
    int sum = c0 + c1;
    s[tid] = sum;
    __syncthreads();
    for (int off = 1; off < 1024; off <<= 1){
        int t = 0;
        if (tid >= off) t = s[tid - off];
        __syncthreads();
        if (tid >= off) s[tid] += t;
        __syncthreads();
    }
    int excl = s[tid] - sum;
    if (2*tid   < NBIN){ offsets[2*tid]   = excl;      off0[2*tid]   = excl; }
    if (2*tid+1 < NBIN){ offsets[2*tid+1] = excl + c0; off0[2*tid+1] = excl + c0; }
    if (tid == 0) off0[NBIN] = NM;
}

// scatter: sorted traj records + inverse permutation (destroys offsets)
__global__ __launch_bounds__(256) void k_scatter(const float* __restrict__ traj,
                                                 const float* __restrict__ dcf,
                                                 int* __restrict__ offsets,
                                                 float4* __restrict__ st,
                                                 int* __restrict__ inv){
    int m = blockIdx.x*256 + threadIdx.x;     // exactly NM threads
    float py = traj[m]      * 640.0f + 320.0f;
    float px = traj[NM + m] * 640.0f + 320.0f;
    int pos = atomicAdd(&offsets[bin_of(py, px)], 1);
    st[pos] = make_float4(py, px, sqrtf(dcf[m]), 0.0f);
    inv[m] = pos;
}

// K3: binned KB degridding through an LDS halo tile. Block = one bin.
// 2 threads per sample (8 coils each); staged[i][16] one 128B line per sample.
__global__ __launch_bounds__(256) void k_interp3(const int* __restrict__ off0,
                                                 const float4* __restrict__ st,
                                                 const float2* __restrict__ kspI,
                                                 float2* __restrict__ staged){
    __shared__ float4 hal[HALO*HALO*8];       // [row][col][coil-quad] = 41472 B
    int b = blockIdx.x;
    int s0 = off0[b];
    int ns = off0[b+1] - s0;
    if (ns == 0) return;
    int by16 = (b / 40) * 16;
    int bx16 = (b - (b/40)*40) * 16;
    int tid = threadIdx.x;
    for (int i = tid; i < HALO*HALO*8; i += 256){
        int rr = i / (HALO*8);
        int rm = i - rr*(HALO*8);
        int j  = rm >> 3;
        int q  = rm & 7;
        int gy = by16 - 1 + rr; if (gy < 0) gy += 640; if (gy >= 640) gy -= 640;
        int gx = bx16 - 1 + j;  if (gx < 0) gx += 640; if (gx >= 640) gx -= 640;
        hal[i] = ((const float4*)(kspI + (gy*640 + gx)*16))[q];
    }
    __syncthreads();
    for (int u = tid; u < 2*ns; u += 256){
        int s = u >> 1;
        int h = u & 1;
        float4 s4 = st[s0 + s];
        float py = s4.x, px = s4.y, sc = s4.z;
        float cy = rintf(py), cx = rintf(px);
        float wy[3], wx[3];
        int ry[3], rx[3];
        #pragma unroll
        for (int j=0;j<3;j++){
            float o = (float)(j-1);
            wy[j] = kbw(cy + o - py);
            wx[j] = kbw(cx + o - px);
            int yy = (int)cy + (j-1) - (by16 - 1);
            if (yy < 0) yy += 640; if (yy >= 640) yy -= 640;
            ry[j] = yy;
            int xx = (int)cx + (j-1) - (bx16 - 1);
            if (xx < 0) xx += 640; if (xx >= 640) xx -= 640;
            rx[j] = xx;
        }
        float2 acc[8];
        #pragma unroll
        for (int c=0;c<8;c++) acc[c] = make_float2(0.0f, 0.0f);
        #pragma unroll
        for (int jy=0;jy<3;jy++){
            #pragma unroll
            for (int jx=0;jx<3;jx++){
                float w = wy[jy]*wx[jx];
                const float4* p = &hal[(ry[jy]*HALO + rx[jx])*8 + h*4];
                #pragma unroll
                for (int q=0;q<4;q++){
                    float4 v = p[q];
                    acc[2*q].x   = fmaf(w, v.x, acc[2*q].x);
                    acc[2*q].y   = fmaf(w, v.y, acc[2*q].y);
                    acc[2*q+1].x = fmaf(w, v.z, acc[2*q+1].x);
                    acc[2*q+1].y = fmaf(w, v.w, acc[2*q+1].y);
                }
            }
        }
        float2* o = staged + (size_t)(s0 + s)*16 + h*8;
        #pragma unroll
        for (int c=0;c<8;c++)
            o[c] = make_float2(acc[c].x*sc, acc[c].y*sc);
    }
}

// un-permute: thread per m reads its full 128B staged line, writes coalesced
__global__ __launch_bounds__(256) void k_unperm(const int* __restrict__ inv,
                                                const float2* __restrict__ staged,
                                                float2* __restrict__ out){
    int m = blockIdx.x*256 + threadIdx.x;     // exactly NM threads
    int j = inv[m];
    const float4* p4 = (const float4*)(staged + (size_t)j*16);
    #pragma unroll
    for (int q=0;q<8;q++){
        float4 v = p4[q];
        out[(2*q)*NM + m]   = make_float2(v.x, v.y);
        out[(2*q+1)*NM + m] = make_float2(v.z, v.w);
    }
}

extern "C" void kernel_launch(void* const* d_in, const int* in_sizes, int n_in,
                              void* d_out, int out_size, void* d_ws, size_t ws_size,
                              hipStream_t stream) {
    (void)in_sizes; (void)n_in; (void)out_size; (void)ws_size;
    const float* x    = (const float*)d_in[0];   // [320,320,2]
    const float* csm  = (const float*)d_in[1];   // [16,320,320,2]
    const float* traj = (const float*)d_in[2];   // [2,204800]
    const float* dcf  = (const float*)d_in[3];   // [204800]
    float* out = (float*)d_out;                  // [16,204800,2]

    char* ws = (char*)d_ws;
    float*  ia1  = (float*)ws;                               // 320 floats
    float2* kspI = (float2*)(ws + 2048);                     // 52.4 MB [640][640][16]
    float2* bufB = (float2*)(ws + 2048 + 52428800ull);       // 26.2 MB [16][640][320]
    float2* staged = bufB;                                   // alias (bufB dead after fft2)
    char* bb = ws + 2048 + 52428800ull + 26214400ull;
    int*    counts  = (int*)bb;                              // 6.4 KB
    int*    offsets = (int*)(bb + 8192);                     // 6.4 KB
    int*    off0    = (int*)(bb + 16384);                    // 6.4 KB (+sentinel)
    int*    inv     = (int*)(bb + 24576);                    // 0.8 MB
    float4* st      = (float4*)(bb + 24576 + 819200);        // 3.3 MB

    // binning
    k_init   <<<1, 1024, 0, stream>>>(ia1, counts);
    k_hist   <<<800, 256, 0, stream>>>(traj, counts);
    k_scan   <<<1, 1024, 0, stream>>>(counts, offsets, off0);
    k_scatter<<<800, 256, 0, stream>>>(traj, dcf, offsets, st, inv);

    // image -> oversampled k-space (prep fused into fft1)
    k_fft1   <<<640, 1024, 0, stream>>>((const float2*)x, (const float2*)csm, ia1, bufB);
    k_fft2   <<<1280, 1024, 0, stream>>>(bufB, kspI);

    // binned degridding + un-permute
    k_interp3<<<NBIN, 256, 0, stream>>>(off0, st, kspI, staged);
    k_unperm <<<800, 256, 0, stream>>>(inv, staged, (float2*)out);
}

// Round 4
// 166.586 us; speedup vs baseline: 1.6365x; 1.0511x over previous
//
#include <hip/hip_runtime.h>
#include <hip/hip_fp16.h>

#define PI_F      3.14159265358979323846f
#define TWO_PI_F  6.28318530717958647692f
#define BETA      6.4860766f     // pi*sqrt((3/2)^2*(1.5)^2 - 0.8)
#define NM        204800
#define TSTRIDE   642
#define NBIN      1600           // 40x40 bins of 16x16 k-space tiles
#define HALO      18

__device__ __forceinline__ float2 cmulf(float2 a, float2 b){
    return make_float2(a.x*b.x - a.y*b.y, a.x*b.y + a.y*b.x);
}

__device__ __forceinline__ float i0_dev(float x){
    if (x < 3.75f){
        float t = x * (1.0f/3.75f); t *= t;
        return 1.0f + t*(3.5156229f + t*(3.0899424f + t*(1.2067492f +
                     t*(0.2659732f + t*(0.0360768f + t*0.0045813f)))));
    } else {
        float u = 3.75f / x;
        float p = 0.39894228f + u*(0.01328592f + u*(0.00225319f + u*(-0.00157565f +
                  u*(0.00916281f + u*(-0.02057706f + u*(0.02635537f +
                  u*(-0.01647633f + u*0.00392377f)))))));
        return p * expf(x) * rsqrtf(x);
    }
}

__device__ __forceinline__ float kbw(float d){
    float dd = d * (2.0f/3.0f);
    float t = 1.0f - dd*dd;
    if (t <= 0.0f) return 0.0f;
    return i0_dev(BETA * sqrtf(t)) * (1.0f/3.0f);
}

// K0: deapod reciprocal profile ia1[320] (= 1/(a1*sqrt(640))) + zero bin counts
__global__ __launch_bounds__(1024) void k_init(float* __restrict__ ia1,
                                               int* __restrict__ counts){
    int i = threadIdx.x;
    if (i < 320){
        float u = (i - 160.0f) * (1.0f/640.0f);
        float v = 3.0f * PI_F * u;
        float q = v*v - BETA*BETA;
        float a;
        if (q >= 0.0f){
            float z = sqrtf(q);
            a = (z > 1e-20f) ? (sinf(z)/z) : 1.0f;
        } else {
            float s = sqrtf(-q);
            a = (expf(s) - expf(-s)) / (2.0f*s);
        }
        ia1[i] = 1.0f / (a * 25.298221281347036f);   // sqrt(640)
    }
    for (int j = i; j < NBIN; j += 1024) counts[j] = 0;
}

// ---- FFT: 8 parallel 640-pt FFTs per 1024-thread block ----
// Entry: tile[f][n] = x[n]. Exit: tile[f][k] = X[k] * (-1)^k.
__device__ __forceinline__ void fft640_core(float2 (*tile)[TSTRIDE],
                                            const float2* __restrict__ tw){
    const int tid = threadIdx.x;
    const int f = tid >> 7;
    const int t = tid & 127;
    float2 r[5];
    {
        float2 xr[5];
        #pragma unroll
        for (int n1=0;n1<5;n1++) xr[n1] = tile[f][t + 128*n1];
        const float c5r[5] = {1.0f, 0.30901699f, -0.80901699f, -0.80901699f, 0.30901699f};
        const float c5i[5] = {0.0f, -0.95105652f, -0.58778525f, 0.58778525f, 0.95105652f};
        #pragma unroll
        for (int k1=0;k1<5;k1++){
            float sx = xr[0].x, sy = xr[0].y;
            #pragma unroll
            for (int n1=1;n1<5;n1++){
                const int j = (n1*k1) % 5;
                sx += xr[n1].x*c5r[j] - xr[n1].y*c5i[j];
                sy += xr[n1].x*c5i[j] + xr[n1].y*c5r[j];
            }
            r[k1] = make_float2(sx, sy);
        }
    }
    #pragma unroll
    for (int k1=1;k1<5;k1++) r[k1] = cmulf(r[k1], tw[t*k1]);

    // stage h=64 (cross-wave) via LDS; w64 = tw[5*(t&63)]
    #pragma unroll
    for (int k1=0;k1<5;k1++) tile[f][k1*128 + t] = r[k1];
    float2 w = tw[(t & 63)*5];
    __syncthreads();
    {
        bool up = (t & 64) != 0;
        #pragma unroll
        for (int k1=0;k1<5;k1++){
            float2 p = tile[f][k1*128 + (t^64)];
            if (!up) r[k1] = make_float2(r[k1].x + p.x, r[k1].y + p.y);
            else     r[k1] = cmulf(make_float2(p.x - r[k1].x, p.y - r[k1].y), w);
        }
    }
    // stages h=32..1 within-wave via shfl_xor; w_h = w_{2h}^2 * (-1)^{(t&h)!=0}
    #pragma unroll
    for (int h=32; h>=1; h >>= 1){
        w = cmulf(w, w);
        bool up = (t & h) != 0;
        if (up){ w.x = -w.x; w.y = -w.y; }
        #pragma unroll
        for (int k1=0;k1<5;k1++){
            float px = __shfl_xor(r[k1].x, h);
            float py = __shfl_xor(r[k1].y, h);
            if (!up) r[k1] = make_float2(r[k1].x + px, r[k1].y + py);
            else     r[k1] = cmulf(make_float2(px - r[k1].x, py - r[k1].y), w);
        }
    }
    __syncthreads();
    int br = __brev((unsigned)t) >> 25;   // bit-reverse 7 bits
    #pragma unroll
    for (int k1=0;k1<5;k1++){
        int g = k1 + 5*br;
        float sg = (g & 1) ? -1.0f : 1.0f;
        tile[f][g] = make_float2(r[k1].x*sg, r[k1].y*sg);
    }
    __syncthreads();
}

// K1: fused prep + FFT along x; write transposed bufB[c][kx][y] as half2
__global__ __launch_bounds__(1024) void k_fft1(const float2* __restrict__ x,
                                               const float2* __restrict__ csm,
                                               const float* __restrict__ ia1,
                                               __half2* __restrict__ bufB){
    __shared__ float2 tile[8][TSTRIDE];
    __shared__ float2 tw[640];
    int b  = blockIdx.x;            // 16 coils * 40 row-octets
    int c  = b / 40;
    int y0 = (b - c*40) * 8;
    int tid = threadIdx.x;
    for (int j = tid; j < 640; j += 1024){
        float sn, cs; sincosf((float)j * (-TWO_PI_F/640.0f), &sn, &cs);
        tw[j] = make_float2(cs, sn);
    }
    for (int idx = tid; idx < 8*640; idx += 1024){
        int f = idx / 640;
        int n = idx - f*640;
        float2 v = make_float2(0.0f, 0.0f);
        if (n >= 160 && n < 480){
            int y  = y0 + f;
            int xi = n - 160;
            int rr = y*320 + xi;
            float2 xv = x[rr];
            float2 cv = csm[c*102400 + rr];
            float scl = ia1[y] * ia1[xi];
            if ((y + xi) & 1) scl = -scl;
            v.x = (cv.x*xv.x - cv.y*xv.y) * scl;
            v.y = (cv.x*xv.y + cv.y*xv.x) * scl;
        }
        tile[f][n] = v;
    }
    __syncthreads();
    fft640_core(tile, tw);
    for (int idx = tid; idx < 640*8; idx += 1024){
        int kx = idx >> 3;
        int f  = idx & 7;
        float2 v = tile[f][kx];
        bufB[(c*640 + kx)*320 + (y0 + f)] = __floats2half2_rn(v.x, v.y);
    }
}

// K2: FFT along y; write coil-interleaved kspH[ky][kx][c] as half2
__global__ __launch_bounds__(1024) void k_fft2(const __half2* __restrict__ bufB,
                                               __half2* __restrict__ kspH){
    __shared__ float2 tile[8][TSTRIDE];
    __shared__ float2 tw[640];
    int b  = blockIdx.x;            // 640 kx * 2 coil-halves
    int kx = b >> 1;
    int c0 = (b & 1) * 8;
    int tid = threadIdx.x;
    for (int j = tid; j < 640; j += 1024){
        float sn, cs; sincosf((float)j * (-TWO_PI_F/640.0f), &sn, &cs);
        tw[j] = make_float2(cs, sn);
    }
    for (int idx = tid; idx < 8*640; idx += 1024){
        int f = idx / 640;
        int n = idx - f*640;
        float2 v = make_float2(0.0f, 0.0f);
        if (n >= 160 && n < 480){
            __half2 hv = bufB[((c0 + f)*640 + kx)*320 + (n - 160)];
            v = make_float2(__low2float(hv), __high2float(hv));
        }
        tile[f][n] = v;
    }
    __syncthreads();
    fft640_core(tile, tw);
    for (int idx = tid; idx < 640*8; idx += 1024){
        int ky = idx >> 3;
        int f  = idx & 7;
        float2 v = tile[f][ky];
        kspH[(ky*640 + kx)*16 + c0 + f] = __floats2half2_rn(v.x, v.y);
    }
}

// ---- binning pipeline ----

__device__ __forceinline__ int bin_of(float py, float px){
    int yy = (int)rintf(py); yy %= 640; if (yy < 0) yy += 640;
    int xx = (int)rintf(px); xx %= 640; if (xx < 0) xx += 640;
    return (yy >> 4) * 40 + (xx >> 4);
}

__global__ __launch_bounds__(256) void k_hist(const float* __restrict__ traj,
                                              int* __restrict__ counts){
    int m = blockIdx.x*256 + threadIdx.x;     // exactly NM threads
    float py = traj[m]      * 640.0f + 320.0f;
    float px = traj[NM + m] * 640.0f + 320.0f;
    atomicAdd(&counts[bin_of(py, px)], 1);
}

// single block: exclusive scan of counts[1600] -> offsets (scratch) + off0 (kept)
__global__ __launch_bounds__(1024) void k_scan(const int* __restrict__ counts,
                                               int* __restrict__ offsets,
                                               int* __restrict__ off0){
    __shared__ int s[1024];
    int tid = threadIdx.x;
    int c0 = (2*tid   < NBIN) ? counts[2*tid]   : 0;
    int c1 = (2*tid+1 < NBIN) ? counts[2*tid+1] : 0;
    int sum = c0 + c1;
    s[tid] = sum;
    __syncthreads();
    for (int off = 1; off < 1024; off <<= 1){
        int t = 0;
        if (tid >= off) t = s[tid - off];
        __syncthreads();
        if (tid >= off) s[tid] += t;
        __syncthreads();
    }
    int excl = s[tid] - sum;
    if (2*tid   < NBIN){ offsets[2*tid]   = excl;      off0[2*tid]   = excl; }
    if (2*tid+1 < NBIN){ offsets[2*tid+1] = excl + c0; off0[2*tid+1] = excl + c0; }
    if (tid == 0) off0[NBIN] = NM;
}

// scatter: sorted traj records + inverse permutation (destroys offsets)
__global__ __launch_bounds__(256) void k_scatter(const float* __restrict__ traj,
                                                 const float* __restrict__ dcf,
                                                 int* __restrict__ offsets,
                                                 float4* __restrict__ st,
                                                 int* __restrict__ inv){
    int m = blockIdx.x*256 + threadIdx.x;     // exactly NM threads
    float py = traj[m]      * 640.0f + 320.0f;
    float px = traj[NM + m] * 640.0f + 320.0f;
    int pos = atomicAdd(&offsets[bin_of(py, px)], 1);
    st[pos] = make_float4(py, px, sqrtf(dcf[m]), 0.0f);
    inv[m] = pos;
}

// K3: binned KB degridding through an LDS halo tile (f32 in LDS, fp16 in HBM).
// Block = one bin; 2 threads per sample (8 coils each); staged[i][16] half2.
__global__ __launch_bounds__(256) void k_interp3(const int* __restrict__ off0,
                                                 const float4* __restrict__ st,
                                                 const __half2* __restrict__ kspH,
                                                 __half2* __restrict__ staged){
    __shared__ float4 hal[HALO*HALO*8];       // [row][col][coil-pair] = 41472 B
    int b = blockIdx.x;
    int s0 = off0[b];
    int ns = off0[b+1] - s0;
    if (ns == 0) return;
    int by16 = (b / 40) * 16;
    int bx16 = (b - (b/40)*40) * 16;
    int tid = threadIdx.x;
    for (int i = tid; i < HALO*HALO*4; i += 256){
        int pt = i >> 2;
        int q  = i & 3;
        int rr = pt / HALO;
        int j  = pt - rr*HALO;
        int gy = by16 - 1 + rr; if (gy < 0) gy += 640; if (gy >= 640) gy -= 640;
        int gx = bx16 - 1 + j;  if (gx < 0) gx += 640; if (gx >= 640) gx -= 640;
        float4 raw = ((const float4*)(kspH + (size_t)(gy*640 + gx)*16))[q];  // 4 coils fp16
        const __half2* hp = (const __half2*)&raw;
        hal[pt*8 + q*2]     = make_float4(__low2float(hp[0]), __high2float(hp[0]),
                                          __low2float(hp[1]), __high2float(hp[1]));
        hal[pt*8 + q*2 + 1] = make_float4(__low2float(hp[2]), __high2float(hp[2]),
                                          __low2float(hp[3]), __high2float(hp[3]));
    }
    __syncthreads();
    for (int u = tid; u < 2*ns; u += 256){
        int s = u >> 1;
        int h = u & 1;
        float4 s4 = st[s0 + s];
        float py = s4.x, px = s4.y, sc = s4.z;
        float cy = rintf(py), cx = rintf(px);
        float wy[3], wx[3];
        int ry[3], rx[3];
        #pragma unroll
        for (int j=0;j<3;j++){
            float o = (float)(j-1);
            wy[j] = kbw(cy + o - py);
            wx[j] = kbw(cx + o - px);
            int yy = (int)cy + (j-1) - (by16 - 1);
            if (yy < 0) yy += 640; if (yy >= 640) yy -= 640;
            ry[j] = yy;
            int xx = (int)cx + (j-1) - (bx16 - 1);
            if (xx < 0) xx += 640; if (xx >= 640) xx -= 640;
            rx[j] = xx;
        }
        float2 acc[8];
        #pragma unroll
        for (int c=0;c<8;c++) acc[c] = make_float2(0.0f, 0.0f);
        #pragma unroll
        for (int jy=0;jy<3;jy++){
            #pragma unroll
            for (int jx=0;jx<3;jx++){
                float w = wy[jy]*wx[jx];
                const float4* p = &hal[(ry[jy]*HALO + rx[jx])*8 + h*4];
                #pragma unroll
                for (int q=0;q<4;q++){
                    float4 v = p[q];
                    acc[2*q].x   = fmaf(w, v.x, acc[2*q].x);
                    acc[2*q].y   = fmaf(w, v.y, acc[2*q].y);
                    acc[2*q+1].x = fmaf(w, v.z, acc[2*q+1].x);
                    acc[2*q+1].y = fmaf(w, v.w, acc[2*q+1].y);
                }
            }
        }
        __half2* o = staged + (size_t)(s0 + s)*16 + h*8;
        #pragma unroll
        for (int c=0;c<8;c++)
            o[c] = __floats2half2_rn(acc[c].x*sc, acc[c].y*sc);
    }
}

// un-permute: thread per m reads its 64B staged line, writes coalesced f32
__global__ __launch_bounds__(256) void k_unperm(const int* __restrict__ inv,
                                                const __half2* __restrict__ staged,
                                                float2* __restrict__ out){
    int m = blockIdx.x*256 + threadIdx.x;     // exactly NM threads
    int j = inv[m];
    const float4* p4 = (const float4*)(staged + (size_t)j*16);
    #pragma unroll
    for (int q=0;q<4;q++){
        float4 raw = p4[q];
        const __half2* hp = (const __half2*)&raw;
        #pragma unroll
        for (int k=0;k<4;k++)
            out[(4*q + k)*NM + m] = make_float2(__low2float(hp[k]), __high2float(hp[k]));
    }
}

extern "C" void kernel_launch(void* const* d_in, const int* in_sizes, int n_in,
                              void* d_out, int out_size, void* d_ws, size_t ws_size,
                              hipStream_t stream) {
    (void)in_sizes; (void)n_in; (void)out_size; (void)ws_size;
    const float* x    = (const float*)d_in[0];   // [320,320,2]
    const float* csm  = (const float*)d_in[1];   // [16,320,320,2]
    const float* traj = (const float*)d_in[2];   // [2,204800]
    const float* dcf  = (const float*)d_in[3];   // [204800]
    float* out = (float*)d_out;                  // [16,204800,2]

    char* ws = (char*)d_ws;
    float*   ia1  = (float*)ws;                              // 1.3 KB
    __half2* kspH = (__half2*)(ws + 2048);                   // 26.2 MB [640][640][16]
    __half2* bufB = (__half2*)(ws + 2048 + 26214400ull);     // 13.1 MB [16][640][320]
    __half2* staged = bufB;                                  // 13.1 MB alias (bufB dead after fft2)
    char* bb = ws + 2048 + 26214400ull + 13107200ull;
    int*    counts  = (int*)bb;                              // 6.4 KB
    int*    offsets = (int*)(bb + 8192);                     // 6.4 KB
    int*    off0    = (int*)(bb + 16384);                    // 6.4 KB (+sentinel)
    int*    inv     = (int*)(bb + 24576);                    // 0.8 MB
    float4* st      = (float4*)(bb + 24576 + 819200);        // 3.3 MB

    // binning
    k_init   <<<1, 1024, 0, stream>>>(ia1, counts);
    k_hist   <<<800, 256, 0, stream>>>(traj, counts);
    k_scan   <<<1, 1024, 0, stream>>>(counts, offsets, off0);
    k_scatter<<<800, 256, 0, stream>>>(traj, dcf, offsets, st, inv);

    // image -> oversampled k-space (prep fused into fft1)
    k_fft1   <<<640, 1024, 0, stream>>>((const float2*)x, (const float2*)csm, ia1, bufB);
    k_fft2   <<<1280, 1024, 0, stream>>>(bufB, kspH);

    // binned degridding + un-permute
    k_interp3<<<NBIN, 256, 0, stream>>>(off0, st, kspH, staged);
    k_unperm <<<800, 256, 0, stream>>>(inv, staged, (float2*)out);
}